// Round 9
// baseline (1651.101 us; speedup 1.0000x reference)
//
#include <hip/hip_runtime.h>
#include <math.h>

// Global state (per chunk of CS samples, sample-major, stride 768):
// HID0 per-sample: l0 @0 (64 [u]), l1 @64 (3x64 [i][u]), l2 @256 (5x64), l1b @576 (3x64)
// HID1 (h1) stride 1536: l0 @0 (128), l1 @128 (3x128), l2 @512 (5x128), l1b @1152 (3x128)

typedef __attribute__((ext_vector_type(8))) short bf16x8;
typedef __attribute__((ext_vector_type(4))) float f32x4;
typedef __attribute__((ext_vector_type(4))) unsigned short u16x4;

__device__ inline f32x4 mfma16(bf16x8 a, bf16x8 b, f32x4 c){
  return __builtin_amdgcn_mfma_f32_16x16x32_bf16(a, b, c, 0, 0, 0);
}
__device__ inline unsigned short f2b(float f){
  union { float f; unsigned u; } v; v.f = f;
  return (unsigned short)((v.u + 0x7fffu + ((v.u >> 16) & 1u)) >> 16);
}
__device__ inline float b2f(unsigned short h){
  union { unsigned u; float f; } v; v.u = ((unsigned)h) << 16; return v.f;
}
__device__ inline void store_hl(unsigned short* ph, unsigned short* pl, int idx, float v){
  unsigned short h = f2b(v);
  ph[idx] = h;
  pl[idx] = f2b(v - b2f(h));
}
// 4 consecutive elements -> one 8B store per plane
__device__ inline void store_hl4(unsigned short* ph, unsigned short* pl, int idx,
                                 float v0, float v1, float v2, float v3){
  u16x4 h, l;
  h[0]=f2b(v0); l[0]=f2b(v0-b2f(h[0]));
  h[1]=f2b(v1); l[1]=f2b(v1-b2f(h[1]));
  h[2]=f2b(v2); l[2]=f2b(v2-b2f(h[2]));
  h[3]=f2b(v3); l[3]=f2b(v3-b2f(h[3]));
  *(u16x4*)(ph+idx) = h;
  *(u16x4*)(pl+idx) = l;
}
#define LDFRAG(p) (*(const bf16x8*)(p))

constexpr int OFF_L2W0 = 0;        // 64x128 (WT[o][k])
constexpr int OFF_L2W1 = 8192;     // 128x256
constexpr int OFF_L2W2 = 40960;    // 64x128
constexpr int OFF_LW0  = 49152;    // 11 x 64x64
constexpr int OFF_LW1  = 94208;    // 11 x 128x128
constexpr int OFF_LW2  = 274432;   // 11 x 64x64
constexpr int OFF_TPW  = 319488;   // 3x14 x 64x64 ([u][v])
constexpr int OFF_TP4W = 491520;   // 17 x 64x64
constexpr int W_TOT    = 561152;

// ============================================================================
// Clebsch-Gordan init (element-parallel fp64; verified R2-R8)
// offsets: 0:(0,0,0)@0 1:(0,1,1)@1 2:(1,0,1)@10 3:(0,2,2)@19 4:(2,0,2)@44
// 5:(1,1,0)@69 6:(1,1,1)@78 7:(1,1,2)@105 8:(2,1,2)@150 9:(1,2,2)@225
// 10:(2,2,0)@300 11:(2,2,1)@325 12:(2,2,2)@400 ; total 525 floats
// ============================================================================
__device__ inline double dfact(int n){ double r=1.0; for(int i=2;i<=n;i++) r*=(double)i; return r; }
struct dcplx { double x, y; };
__device__ inline dcplx cmul(dcplx a, dcplx b){ return {a.x*b.x-a.y*b.y, a.x*b.y+a.y*b.x}; }

__device__ dcplx Uent(int l, int r, int c){
  double re=0.0, im=0.0;
  double s = 1.0/sqrt(2.0);
  if (r==l && c==l) re = 1.0;
  else if (c>l){ int m=c-l; double sgn=(m&1)?-1.0:1.0;
    if (r==l-m) re = s; else if (r==l+m) re = sgn*s;
  } else if (c<l){ int m=l-c; double sgn=(m&1)?-1.0:1.0;
    if (r==l-m) im = s; else if (r==l+m) im = -sgn*s;
  }
  int lm=l&3; double pr,pi;
  if(lm==0){pr=1;pi=0;} else if(lm==1){pr=0;pi=-1;} else if(lm==2){pr=-1;pi=0;} else {pr=0;pi=1;}
  return { re*pr-im*pi, re*pi+im*pr };
}

__device__ double cg_complex_entry(int l1,int l2,int l3,int m1,int m2){
  int m3=m1+m2;
  if (m3<-l3 || m3>l3) return 0.0;
  double pref = sqrt((double)(2*l3+1)*dfact(l3+l1-l2)*dfact(l3-l1+l2)*dfact(l1+l2-l3)/dfact(l1+l2+l3+1));
  pref *= sqrt(dfact(l3+m3)*dfact(l3-m3)*dfact(l1-m1)*dfact(l1+m1)*dfact(l2-m2)*dfact(l2+m2));
  double s=0.0;
  for(int k=0;k<=l1+l2-l3;k++){
    int a2=l1-m1-k, a3=l2+m2-k, a4=l3-l2+m1+k, a5=l3-l1-m2+k;
    if(a2<0||a3<0||a4<0||a5<0) continue;
    double t=1.0/(dfact(k)*dfact(l1+l2-l3-k)*dfact(a2)*dfact(a3)*dfact(a4)*dfact(a5));
    s += (k&1)? -t : t;
  }
  return pref*s;
}

__global__ void cg_init_kernel(float* cg){
  __shared__ double sKr[525], sKi[525];
  __shared__ double sScale[13];
  __shared__ int    sSel[13];
  const int L1[13]={0,0,1,0,2,1,1,1,2,1,2,2,2};
  const int L2[13]={0,1,0,2,0,1,1,1,1,2,2,2,2};
  const int L3[13]={0,1,1,2,2,0,1,2,2,2,0,1,2};
  const int OFF[14]={0,1,10,19,44,69,78,105,150,225,300,325,400,525};
  const int tid = threadIdx.x;
  int combo=-1, l1=0,l2=0,l3=0;
  if (tid < 525){
    combo=12;
    for(int i=0;i<12;i++) if (tid < OFF[i+1]) { combo=i; break; }
    l1=L1[combo]; l2=L2[combo]; l3=L3[combo];
    int d2=2*l2+1, d3=2*l3+1;
    int e = tid - OFF[combo];
    int a = e/(d2*d3), b=(e/d3)%d2, cc=e%d3;
    double kr=0.0, ki=0.0;
    for(int m=0;m<2*l1+1;m++) for(int n=0;n<d2;n++){
      int m3 = (m-l1)+(n-l2);
      if (m3<-l3||m3>l3) continue;
      double cv = cg_complex_entry(l1,l2,l3,m-l1,n-l2);
      if (cv==0.0) continue;
      dcplx u1=Uent(l1,m,a), u2=Uent(l2,n,b), u3=Uent(l3,m3+l3,cc);
      u3.y = -u3.y;
      dcplx t = cmul(cmul(u1,u2),u3);
      kr += t.x*cv; ki += t.y*cv;
    }
    sKr[tid]=kr; sKi[tid]=ki;
  }
  __syncthreads();
  if (tid < 13){
    int sz = OFF[tid+1]-OFF[tid];
    double nr=0,ni=0;
    for(int i=0;i<sz;i++){ double r=sKr[OFF[tid]+i], im=sKi[OFF[tid]+i]; nr+=r*r; ni+=im*im; }
    int sel = (nr>=ni)? 0 : 1;
    sSel[tid]=sel;
    sScale[tid] = sqrt((double)(2*L3[tid]+1))/sqrt(sel? ni : nr);
  }
  __syncthreads();
  if (tid < 525){
    double v = sSel[combo]? sKi[tid] : sKr[tid];
    cg[tid] = (float)(v*sScale[combo]);
  }
}

// ============================================================================
// Weight prep: fp32 -> bf16 hi/lo planes (WT[o][k] for linears, [u][v] for TP)
// ============================================================================
__global__ void prep_kernel(const float* __restrict__ l2W0, const float* __restrict__ l2W1,
                            const float* __restrict__ l2W2, const float* __restrict__ LW0,
                            const float* __restrict__ LW1, const float* __restrict__ LW2,
                            const float* __restrict__ tpw, const float* __restrict__ tp4w,
                            unsigned short* __restrict__ wb){
  int i = blockIdx.x*256 + threadIdx.x;
  if (i >= W_TOT) return;
  float v;
  if (i < 8192){ int o=i>>7, k=i&127; v = l2W0[k*64+o]; }
  else if (i < 40960){ int j=i-8192; int o=j>>8, k=j&255; v = l2W1[k*128+o]; }
  else if (i < 49152){ int j=i-40960; int o=j>>7, k=j&127; v = l2W2[k*64+o]; }
  else if (i < 94208){ int j=i-49152; int li=j>>12, r=j&4095, o=r>>6, k=r&63; v = LW0[li*4096+k*64+o]; }
  else if (i < 274432){ int j=i-94208; int li=j>>14, r=j&16383, o=r>>7, k=r&127; v = LW1[li*16384+k*128+o]; }
  else if (i < 319488){ int j=i-274432; int li=j>>12, r=j&4095, o=r>>6, k=r&63; v = LW2[li*4096+k*64+o]; }
  else if (i < 491520){ v = tpw[i-319488]; }
  else { v = tp4w[i-491520]; }
  unsigned short h = f2b(v);
  wb[i] = h;
  wb[W_TOT + i] = f2b(v - b2f(h));
}

// ============================================================================
// lin1: x (fp32, 80) -> h1 (hi/lo bf16, stride 1536). One block per sample.
// ============================================================================
__global__ __launch_bounds__(256) void lin1_kernel(
    const float* __restrict__ x,
    const float* __restrict__ l1W0, const float* __restrict__ l1W1,
    const float* __restrict__ l1W2, const float* __restrict__ l1b0,
    unsigned short* __restrict__ h1h, unsigned short* __restrict__ h1l, int nb)
{
  const float rs8 = 0.3535533905932738f;
  int n = blockIdx.x;
  const float* xp = x + (size_t)(nb + n)*80;
  for (int c = threadIdx.x; c < 1536; c += 256){
    float acc = 0.f;
    if (c < 128){
      #pragma unroll
      for (int v=0;v<16;v++) acc += xp[v]*l1W0[v*128+c];
      acc = acc*0.25f + l1b0[c];
    } else if (c < 512){
      int i=(c-128)>>7, o=(c-128)&127;
      #pragma unroll
      for (int v=0;v<8;v++) acc += xp[16+v*3+i]*l1W1[v*256+o];
      acc *= rs8;
    } else if (c < 1152){
      int i=(c-512)>>7, o=(c-512)&127;
      #pragma unroll
      for (int v=0;v<8;v++) acc += xp[40+v*5+i]*l1W2[v*128+o];
      acc *= rs8;
    } else {
      int i=(c-1152)>>7, o=(c-1152)&127;
      #pragma unroll
      for (int v=0;v<8;v++) acc += xp[16+v*3+i]*l1W1[v*256+128+o];
      acc *= rs8;
    }
    store_hl(h1h, h1l, n*1536 + c, acc);
  }
}

// ============================================================================
// lin2: h1 (1536) -> HID0 (768). A=weights, B=state; D[outcomp][sample] ->
// u16x4 stores. grid (CS/16, 4); job = y*4+wave.
// ============================================================================
__global__ __launch_bounds__(256) void lin2k_kernel(
    const unsigned short* __restrict__ wb, const float* __restrict__ b0,
    const unsigned short* __restrict__ sh, const unsigned short* __restrict__ sl,
    unsigned short* __restrict__ dh, unsigned short* __restrict__ dl)
{
  const float rs128 = 0.08838834764831845f;
  int lane = threadIdx.x & 63, wave = threadIdx.x >> 6;
  int job = blockIdx.y*4 + wave;
  int l16 = lane & 15, quad = lane >> 4;
  int nb16 = blockIdx.x*16;
  int arow = (nb16 + l16)*1536;
  int drow = (nb16 + l16)*768;
  if (job < 4){                 // l0: K=128, /sqrt(128) + bias
    int col16 = job*16;
    f32x4 a0 = {0,0,0,0}, a1 = {0,0,0,0};
    #pragma unroll
    for (int ks=0; ks<4; ks++){
      int ko = ks*32 + quad*8;
      bf16x8 xh = LDFRAG(sh+arow+ko), xl = LDFRAG(sl+arow+ko);
      int wo = OFF_L2W0 + (col16+l16)*128 + ko;
      bf16x8 wh = LDFRAG(wb+wo), wl = LDFRAG(wb+W_TOT+wo);
      a0 = mfma16(wh,xh,a0); a1 = mfma16(wh,xl,a1); a1 = mfma16(wl,xh,a1);
    }
    int colq = col16 + quad*4;
    f32x4 bi = *(const f32x4*)(b0 + colq);
    store_hl4(dh,dl, drow + colq,
      (a0[0]+a1[0])*rs128 + bi[0], (a0[1]+a1[1])*rs128 + bi[1],
      (a0[2]+a1[2])*rs128 + bi[2], (a0[3]+a1[3])*rs128 + bi[3]);
  } else if (job < 12){         // l1: K=256 (l1|l1b), /16
    int col16 = (job-4)*16;
    #pragma unroll
    for (int i=0;i<3;i++){
      f32x4 a0 = {0,0,0,0}, a1 = {0,0,0,0};
      #pragma unroll
      for (int ks=0; ks<8; ks++){
        int ka = ks*32 + quad*8;
        int so = arow + ((ka < 128) ? (128 + i*128 + ka) : (1152 + i*128 + ka - 128));
        bf16x8 xh = LDFRAG(sh+so), xl = LDFRAG(sl+so);
        int wo = OFF_L2W1 + (col16+l16)*256 + ka;
        bf16x8 wh = LDFRAG(wb+wo), wl = LDFRAG(wb+W_TOT+wo);
        a0 = mfma16(wh,xh,a0); a1 = mfma16(wh,xl,a1); a1 = mfma16(wl,xh,a1);
      }
      int colq = col16 + quad*4;
      int dof = (colq < 64) ? (64 + i*64 + colq) : (576 + i*64 + colq - 64);
      store_hl4(dh,dl, drow + dof,
        (a0[0]+a1[0])*0.0625f, (a0[1]+a1[1])*0.0625f,
        (a0[2]+a1[2])*0.0625f, (a0[3]+a1[3])*0.0625f);
    }
  } else {                      // l2: K=128, /sqrt(128)
    int col16 = (job-12)*16;
    #pragma unroll
    for (int i=0;i<5;i++){
      f32x4 a0 = {0,0,0,0}, a1 = {0,0,0,0};
      #pragma unroll
      for (int ks=0; ks<4; ks++){
        int so = arow + 512 + i*128 + ks*32 + quad*8;
        bf16x8 xh = LDFRAG(sh+so), xl = LDFRAG(sl+so);
        int wo = OFF_L2W2 + (col16+l16)*128 + ks*32 + quad*8;
        bf16x8 wh = LDFRAG(wb+wo), wl = LDFRAG(wb+W_TOT+wo);
        a0 = mfma16(wh,xh,a0); a1 = mfma16(wh,xl,a1); a1 = mfma16(wl,xh,a1);
      }
      int colq = col16 + quad*4;
      store_hl4(dh,dl, drow + 256 + i*64 + colq,
        (a0[0]+a1[0])*rs128, (a0[1]+a1[1])*rs128,
        (a0[2]+a1[2])*rs128, (a0[3]+a1[3])*rs128);
    }
  }
}

// ============================================================================
// HID0 -> HID0 linear, optionally dual-output (shares B-state fragments).
// A=weights, B=state; u16x4 stores. grid (CS/16, 4); job = y*4+wave.
// ============================================================================
template<bool DUAL>
__global__ __launch_bounds__(256) void linh_t(
    const unsigned short* __restrict__ wb,
    const unsigned short* __restrict__ sh, const unsigned short* __restrict__ sl,
    int o0a, int o1a, int o2a, const float* __restrict__ b0a,
    unsigned short* __restrict__ dah, unsigned short* __restrict__ dal,
    int o0b, int o1b, int o2b, const float* __restrict__ b0b,
    unsigned short* __restrict__ dbh, unsigned short* __restrict__ dbl)
{
  const float rs128 = 0.08838834764831845f;
  int lane = threadIdx.x & 63, wave = threadIdx.x >> 6;
  int job = blockIdx.y*4 + wave;
  int l16 = lane & 15, quad = lane >> 4;
  int nb16 = blockIdx.x*16;
  int srow = (nb16 + l16)*768;
  if (job < 4){                 // l0: K=64, /8 + bias
    int col16 = job*16;
    f32x4 pa0={0,0,0,0}, pa1={0,0,0,0}, pb0={0,0,0,0}, pb1={0,0,0,0};
    #pragma unroll
    for (int ks=0; ks<2; ks++){
      int ko = ks*32 + quad*8;
      bf16x8 xh = LDFRAG(sh+srow+ko), xl = LDFRAG(sl+srow+ko);
      int wa = o0a + (col16+l16)*64 + ko;
      bf16x8 wha = LDFRAG(wb+wa), wla = LDFRAG(wb+W_TOT+wa);
      pa0 = mfma16(wha,xh,pa0); pa1 = mfma16(wha,xl,pa1); pa1 = mfma16(wla,xh,pa1);
      if constexpr(DUAL){
        int wo = o0b + (col16+l16)*64 + ko;
        bf16x8 whb = LDFRAG(wb+wo), wlb = LDFRAG(wb+W_TOT+wo);
        pb0 = mfma16(whb,xh,pb0); pb1 = mfma16(whb,xl,pb1); pb1 = mfma16(wlb,xh,pb1);
      }
    }
    int colq = col16 + quad*4;
    f32x4 ba = *(const f32x4*)(b0a + colq);
    store_hl4(dah,dal, srow + colq,
      (pa0[0]+pa1[0])*0.125f + ba[0], (pa0[1]+pa1[1])*0.125f + ba[1],
      (pa0[2]+pa1[2])*0.125f + ba[2], (pa0[3]+pa1[3])*0.125f + ba[3]);
    if constexpr(DUAL){
      f32x4 bb = *(const f32x4*)(b0b + colq);
      store_hl4(dbh,dbl, srow + colq,
        (pb0[0]+pb1[0])*0.125f + bb[0], (pb0[1]+pb1[1])*0.125f + bb[1],
        (pb0[2]+pb1[2])*0.125f + bb[2], (pb0[3]+pb1[3])*0.125f + bb[3]);
    }
  } else if (job < 12){         // l1: K=128 (l1|l1b), /sqrt(128)
    int col16 = (job-4)*16;
    #pragma unroll
    for (int i=0;i<3;i++){
      f32x4 pa0={0,0,0,0}, pa1={0,0,0,0}, pb0={0,0,0,0}, pb1={0,0,0,0};
      #pragma unroll
      for (int ks=0; ks<4; ks++){
        int ka = ks*32 + quad*8;
        int so = srow + ((ka < 64) ? (64 + i*64 + ka) : (576 + i*64 + ka - 64));
        bf16x8 xh = LDFRAG(sh+so), xl = LDFRAG(sl+so);
        int wa = o1a + (col16+l16)*128 + ka;
        bf16x8 wha = LDFRAG(wb+wa), wla = LDFRAG(wb+W_TOT+wa);
        pa0 = mfma16(wha,xh,pa0); pa1 = mfma16(wha,xl,pa1); pa1 = mfma16(wla,xh,pa1);
        if constexpr(DUAL){
          int wo = o1b + (col16+l16)*128 + ka;
          bf16x8 whb = LDFRAG(wb+wo), wlb = LDFRAG(wb+W_TOT+wo);
          pb0 = mfma16(whb,xh,pb0); pb1 = mfma16(whb,xl,pb1); pb1 = mfma16(wlb,xh,pb1);
        }
      }
      int colq = col16 + quad*4;
      int dof = (colq < 64) ? (64 + i*64 + colq) : (576 + i*64 + colq - 64);
      store_hl4(dah,dal, srow + dof,
        (pa0[0]+pa1[0])*rs128, (pa0[1]+pa1[1])*rs128,
        (pa0[2]+pa1[2])*rs128, (pa0[3]+pa1[3])*rs128);
      if constexpr(DUAL)
        store_hl4(dbh,dbl, srow + dof,
          (pb0[0]+pb1[0])*rs128, (pb0[1]+pb1[1])*rs128,
          (pb0[2]+pb1[2])*rs128, (pb0[3]+pb1[3])*rs128);
    }
  } else {                      // l2: K=64, /8
    int col16 = (job-12)*16;
    #pragma unroll
    for (int i=0;i<5;i++){
      f32x4 pa0={0,0,0,0}, pa1={0,0,0,0}, pb0={0,0,0,0}, pb1={0,0,0,0};
      #pragma unroll
      for (int ks=0; ks<2; ks++){
        int so = srow + 256 + i*64 + ks*32 + quad*8;
        bf16x8 xh = LDFRAG(sh+so), xl = LDFRAG(sl+so);
        int wa = o2a + (col16+l16)*64 + ks*32 + quad*8;
        bf16x8 wha = LDFRAG(wb+wa), wla = LDFRAG(wb+W_TOT+wa);
        pa0 = mfma16(wha,xh,pa0); pa1 = mfma16(wha,xl,pa1); pa1 = mfma16(wla,xh,pa1);
        if constexpr(DUAL){
          int wo = o2b + (col16+l16)*64 + ks*32 + quad*8;
          bf16x8 whb = LDFRAG(wb+wo), wlb = LDFRAG(wb+W_TOT+wo);
          pb0 = mfma16(whb,xh,pb0); pb1 = mfma16(whb,xl,pb1); pb1 = mfma16(wlb,xh,pb1);
        }
      }
      int colq = col16 + quad*4;
      store_hl4(dah,dal, srow + 256 + i*64 + colq,
        (pa0[0]+pa1[0])*0.125f, (pa0[1]+pa1[1])*0.125f,
        (pa0[2]+pa1[2])*0.125f, (pa0[3]+pa1[3])*0.125f);
      if constexpr(DUAL)
        store_hl4(dbh,dbl, srow + 256 + i*64 + colq,
          (pb0[0]+pb1[0])*0.125f, (pb0[1]+pb1[1])*0.125f,
          (pb0[2]+pb1[2])*0.125f, (pb0[3]+pb1[3])*0.125f);
    }
  }
}

// ============================================================================
// TP path: wave mt computes b = W(rows mt*16..+16) x x2 with hi/lo MFMA; D
// fragment sits at (u=mt*16+quad*4+r, n=l16) so CG contraction consumes it
// from registers. j-loop not unrolled (keeps VGPR pressure low).
// ============================================================================
template<int D1,int D2,int D3,int O1,int O2,int CGO>
__device__ __forceinline__ void tpg_path(
    const unsigned short* __restrict__ wb, int wo,
    const unsigned short* __restrict__ s1h, const unsigned short* __restrict__ s1l,
    const unsigned short* __restrict__ s2h, const unsigned short* __restrict__ s2l,
    const float* __restrict__ cgp, float* tk, int mt, int l16, int quad, int n)
{
  float x1v[4][D1];
  int ub = mt*16 + quad*4;
  #pragma unroll
  for (int i=0;i<D1;i++){
    int o = n*768 + O1 + i*64 + ub;
    u16x4 hs = *(const u16x4*)(s1h + o);
    u16x4 ls = *(const u16x4*)(s1l + o);
    #pragma unroll
    for (int r=0;r<4;r++) x1v[r][i] = b2f(hs[r]) + b2f(ls[r]);
  }
  #pragma clang loop unroll(disable)
  for (int j=0;j<D2;j++){
    f32x4 a0 = {0,0,0,0}, a1 = {0,0,0,0};
    #pragma unroll
    for (int ks=0;ks<2;ks++){
      int wofs = wo + (mt*16 + l16)*64 + ks*32 + quad*8;
      bf16x8 wh = LDFRAG(wb + wofs), wl = LDFRAG(wb + W_TOT + wofs);
      int sofs = n*768 + O2 + j*64 + ks*32 + quad*8;
      bf16x8 xh = LDFRAG(s2h + sofs), xl = LDFRAG(s2l + sofs);
      a0 = mfma16(wh,xh,a0); a1 = mfma16(wh,xl,a1); a1 = mfma16(wl,xh,a1);
    }
    #pragma unroll
    for (int r=0;r<4;r++){
      float bv = a0[r] + a1[r];
      #pragma unroll
      for (int i=0;i<D1;i++){
        float pr = x1v[r][i]*bv;
        #pragma unroll
        for (int k=0;k<D3;k++) tk[r*D3+k] += pr*cgp[CGO + (i*D2+j)*D3 + k];
      }
    }
  }
}

// uvu TP. grid (CS/16, 4): blockIdx.y = output group. No barriers.
__global__ __launch_bounds__(256) void tpu_kernel(
    const unsigned short* __restrict__ wb, int two,
    const unsigned short* __restrict__ s1h, const unsigned short* __restrict__ s1l,
    const unsigned short* __restrict__ s2h, const unsigned short* __restrict__ s2l,
    unsigned short* __restrict__ dh, unsigned short* __restrict__ dl,
    const float* __restrict__ cgp)
{
  const float f192 = 0.07216878364870323f;  // 1/sqrt(192)
  const float f256 = 0.0625f;               // 1/sqrt(256)
  int lane = threadIdx.x & 63, mt = threadIdx.x >> 6;
  int l16 = lane & 15, quad = lane >> 4;
  int n = blockIdx.x*16 + l16;
  int ub = mt*16 + quad*4;
  int g = blockIdx.y;
  if (g == 0){        // out l0 @0 (fan 192): paths 0,5,10
    float tk[4]; for (int i=0;i<4;i++) tk[i]=0.f;
    tpg_path<1,1,1,  0,  0,  0>(wb,two+ 0*4096, s1h,s1l,s2h,s2l,cgp,tk,mt,l16,quad,n);
    tpg_path<3,3,1, 64, 64, 69>(wb,two+ 5*4096, s1h,s1l,s2h,s2l,cgp,tk,mt,l16,quad,n);
    tpg_path<5,5,1,256,256,300>(wb,two+10*4096, s1h,s1l,s2h,s2l,cgp,tk,mt,l16,quad,n);
    store_hl4(dh,dl, n*768 + ub, tk[0]*f192, tk[1]*f192, tk[2]*f192, tk[3]*f192);
  } else if (g == 1){ // out l1 @64 (fan 256): paths 1,4,6,11
    float tk[12]; for (int i=0;i<12;i++) tk[i]=0.f;
    tpg_path<1,3,3,  0, 64,  1>(wb,two+ 1*4096, s1h,s1l,s2h,s2l,cgp,tk,mt,l16,quad,n);
    tpg_path<3,1,3, 64,  0, 10>(wb,two+ 4*4096, s1h,s1l,s2h,s2l,cgp,tk,mt,l16,quad,n);
    tpg_path<3,3,3, 64, 64, 78>(wb,two+ 6*4096, s1h,s1l,s2h,s2l,cgp,tk,mt,l16,quad,n);
    tpg_path<5,5,3,256,256,325>(wb,two+11*4096, s1h,s1l,s2h,s2l,cgp,tk,mt,l16,quad,n);
    #pragma unroll
    for (int k=0;k<3;k++)
      store_hl4(dh,dl, n*768 + 64 + k*64 + ub,
        tk[0*3+k]*f256, tk[1*3+k]*f256, tk[2*3+k]*f256, tk[3*3+k]*f256);
  } else if (g == 2){ // out l2 @256 (fan 256): paths 2,8,9,13
    float tk[20]; for (int i=0;i<20;i++) tk[i]=0.f;
    tpg_path<1,5,5,  0,256, 19>(wb,two+ 2*4096, s1h,s1l,s2h,s2l,cgp,tk,mt,l16,quad,n);
    tpg_path<5,1,5,256,  0, 44>(wb,two+ 8*4096, s1h,s1l,s2h,s2l,cgp,tk,mt,l16,quad,n);
    tpg_path<5,3,5,256, 64,150>(wb,two+ 9*4096, s1h,s1l,s2h,s2l,cgp,tk,mt,l16,quad,n);
    tpg_path<5,3,5,256,576,150>(wb,two+13*4096, s1h,s1l,s2h,s2l,cgp,tk,mt,l16,quad,n);
    #pragma unroll
    for (int k=0;k<5;k++)
      store_hl4(dh,dl, n*768 + 256 + k*64 + ub,
        tk[0*5+k]*f256, tk[1*5+k]*f256, tk[2*5+k]*f256, tk[3*5+k]*f256);
  } else {            // out l1b @576 (fan 192): paths 3,7,12
    float tk[12]; for (int i=0;i<12;i++) tk[i]=0.f;
    tpg_path<1,3,3,  0,576,  1>(wb,two+ 3*4096, s1h,s1l,s2h,s2l,cgp,tk,mt,l16,quad,n);
    tpg_path<3,3,3, 64, 64, 78>(wb,two+ 7*4096, s1h,s1l,s2h,s2l,cgp,tk,mt,l16,quad,n);
    tpg_path<5,5,3,256,256,325>(wb,two+12*4096, s1h,s1l,s2h,s2l,cgp,tk,mt,l16,quad,n);
    #pragma unroll
    for (int k=0;k<3;k++)
      store_hl4(dh,dl, n*768 + 576 + k*64 + ub,
        tk[0*3+k]*f192, tk[1*3+k]*f192, tk[2*3+k]*f192, tk[3*3+k]*f192);
  }
}

// fully-connected TP -> out. grid (CS/16, 2): blockIdx.y = output slot.
__global__ __launch_bounds__(256) void tpf_kernel(
    const unsigned short* __restrict__ wb,
    const unsigned short* __restrict__ s1h, const unsigned short* __restrict__ s1l,
    const unsigned short* __restrict__ s2h, const unsigned short* __restrict__ s2l,
    const float* __restrict__ cgp, float* __restrict__ out, int nb)
{
  __shared__ float red[4][16][5];
  int lane = threadIdx.x & 63, mt = threadIdx.x >> 6;
  int l16 = lane & 15, quad = lane >> 4;
  int n = blockIdx.x*16 + l16;
  if (blockIdx.y == 0){ // out 0e (slot 0): fc paths 0..5
    float tk[4]; for (int i=0;i<4;i++) tk[i]=0.f;
    tpg_path<1,1,1,  0,  0,  0>(wb,OFF_TP4W+ 0*4096, s1h,s1l,s2h,s2l,cgp,tk,mt,l16,quad,n);
    tpg_path<3,3,1, 64, 64, 69>(wb,OFF_TP4W+ 1*4096, s1h,s1l,s2h,s2l,cgp,tk,mt,l16,quad,n);
    tpg_path<3,3,1, 64,576, 69>(wb,OFF_TP4W+ 2*4096, s1h,s1l,s2h,s2l,cgp,tk,mt,l16,quad,n);
    tpg_path<5,5,1,256,256,300>(wb,OFF_TP4W+ 3*4096, s1h,s1l,s2h,s2l,cgp,tk,mt,l16,quad,n);
    tpg_path<3,3,1,576, 64, 69>(wb,OFF_TP4W+ 4*4096, s1h,s1l,s2h,s2l,cgp,tk,mt,l16,quad,n);
    tpg_path<3,3,1,576,576, 69>(wb,OFF_TP4W+ 5*4096, s1h,s1l,s2h,s2l,cgp,tk,mt,l16,quad,n);
    float t = tk[0]+tk[1]+tk[2]+tk[3];
    t += __shfl_down(t, 32, 64);
    t += __shfl_down(t, 16, 64);
    if (lane < 16) red[mt][l16][0] = t;
    __syncthreads();
    if (threadIdx.x < 16){
      float s = red[0][threadIdx.x][0] + red[1][threadIdx.x][0]
              + red[2][threadIdx.x][0] + red[3][threadIdx.x][0];
      out[(size_t)(nb + blockIdx.x*16 + threadIdx.x)*6] = s*(1.0f/sqrtf(24576.0f));
    }
  } else {              // out 2e (slots 1..5): fc paths 6..16
    float tk[20]; for (int i=0;i<20;i++) tk[i]=0.f;
    tpg_path<1,5,5,  0,256, 19>(wb,OFF_TP4W+ 6*4096, s1h,s1l,s2h,s2l,cgp,tk,mt,l16,quad,n);
    tpg_path<3,3,5, 64, 64,105>(wb,OFF_TP4W+ 7*4096, s1h,s1l,s2h,s2l,cgp,tk,mt,l16,quad,n);
    tpg_path<3,5,5, 64,256,225>(wb,OFF_TP4W+ 8*4096, s1h,s1l,s2h,s2l,cgp,tk,mt,l16,quad,n);
    tpg_path<3,3,5, 64,576,105>(wb,OFF_TP4W+ 9*4096, s1h,s1l,s2h,s2l,cgp,tk,mt,l16,quad,n);
    tpg_path<5,1,5,256,  0, 44>(wb,OFF_TP4W+10*4096, s1h,s1l,s2h,s2l,cgp,tk,mt,l16,quad,n);
    tpg_path<5,3,5,256, 64,150>(wb,OFF_TP4W+11*4096, s1h,s1l,s2h,s2l,cgp,tk,mt,l16,quad,n);
    tpg_path<5,5,5,256,256,400>(wb,OFF_TP4W+12*4096, s1h,s1l,s2h,s2l,cgp,tk,mt,l16,quad,n);
    tpg_path<5,3,5,256,576,150>(wb,OFF_TP4W+13*4096, s1h,s1l,s2h,s2l,cgp,tk,mt,l16,quad,n);
    tpg_path<3,3,5,576, 64,105>(wb,OFF_TP4W+14*4096, s1h,s1l,s2h,s2l,cgp,tk,mt,l16,quad,n);
    tpg_path<3,5,5,576,256,225>(wb,OFF_TP4W+15*4096, s1h,s1l,s2h,s2l,cgp,tk,mt,l16,quad,n);
    tpg_path<3,3,5,576,576,105>(wb,OFF_TP4W+16*4096, s1h,s1l,s2h,s2l,cgp,tk,mt,l16,quad,n);
    #pragma unroll
    for (int k=0;k<5;k++){
      float t = tk[k] + tk[5+k] + tk[10+k] + tk[15+k];
      t += __shfl_down(t, 32, 64);
      t += __shfl_down(t, 16, 64);
      if (lane < 16) red[mt][l16][k] = t;
    }
    __syncthreads();
    if (threadIdx.x < 80){
      int n2 = threadIdx.x/5, k = threadIdx.x%5;
      float s = red[0][n2][k] + red[1][n2][k] + red[2][n2][k] + red[3][n2][k];
      out[(size_t)(nb + blockIdx.x*16 + n2)*6 + 1 + k] = s*(1.0f/sqrtf(45056.0f));
    }
  }
}

// ============================================================================
extern "C" void kernel_launch(void* const* d_in, const int* in_sizes, int n_in,
                              void* d_out, int out_size, void* d_ws, size_t ws_size,
                              hipStream_t stream)
{
  (void)n_in; (void)out_size;
  const float* x    = (const float*)d_in[0];
  const float* l1W0 = (const float*)d_in[1];
  const float* l1W1 = (const float*)d_in[2];
  const float* l1W2 = (const float*)d_in[3];
  const float* l1b0 = (const float*)d_in[4];
  const float* l2W0 = (const float*)d_in[5];
  const float* l2W1 = (const float*)d_in[6];
  const float* l2W2 = (const float*)d_in[7];
  const float* l2b0 = (const float*)d_in[8];
  const float* LW0  = (const float*)d_in[9];
  const float* LW1  = (const float*)d_in[10];
  const float* LW2  = (const float*)d_in[11];
  const float* Lb0  = (const float*)d_in[12];
  const float* tpw  = (const float*)d_in[13];
  const float* tp4w = (const float*)d_in[14];

  float* cg = (float*)d_ws;                                    // 525 f32 @ ws+0
  unsigned short* wbp = (unsigned short*)((char*)d_ws + 4096); // hi+lo weights
  size_t base = 4096 + (size_t)2*W_TOT*2;
  base = (base + 255) & ~(size_t)255;
  unsigned short* st = (unsigned short*)((char*)d_ws + base);
  size_t avail = (ws_size > base) ? (ws_size - base) : 0;

  const int total = in_sizes[0]/80;    // 16384
  int nch = 1, CS = total;
  while (CS > 4096){ nch <<= 1; CS >>= 1; }               // L3-residency cap
  while (CS > 16 && (size_t)CS * 9216 > avail){ nch <<= 1; CS >>= 1; }
  size_t P = (size_t)CS * 768;         // elements per plane

  cg_init_kernel<<<1, 576, 0, stream>>>(cg);
  prep_kernel<<<(W_TOT+255)/256, 256, 0, stream>>>(l2W0,l2W1,l2W2,LW0,LW1,LW2,tpw,tp4w,wbp);

  #define BH(b) (st + (size_t)(2*(b))*P)
  #define BL(b) (st + (size_t)(2*(b)+1)*P)
  #define LO0(i) (OFF_LW0+(i)*4096)
  #define LO1(i) (OFF_LW1+(i)*16384)
  #define LO2(i) (OFF_LW2+(i)*4096)
  for (int c = 0; c < nch; c++){
    int nb = c*CS;
    unsigned short* h1h = st;          // buffers 0+1 hi+lo regions (4P total)
    unsigned short* h1l = st + 2*P;

    lin1_kernel<<<CS, 256, 0, stream>>>(x, l1W0,l1W1,l1W2,l1b0, h1h,h1l, nb);
    lin2k_kernel<<<dim3(CS/16,4), 256, 0, stream>>>(wbp, l2b0, h1h,h1l, BH(2),BL(2));

    int ih=2, i0=0, i1=1;
    for (int r=0;r<3;r++){
      linh_t<true><<<dim3(CS/16,4), 256, 0, stream>>>(wbp, BH(ih),BL(ih),
          LO0(3*r), LO1(3*r), LO2(3*r), Lb0+(3*r)*64, BH(i0),BL(i0),
          LO0(3*r+1), LO1(3*r+1), LO2(3*r+1), Lb0+(3*r+1)*64, BH(i1),BL(i1));
      tpu_kernel<<<dim3(CS/16,4), 256, 0, stream>>>(wbp, OFF_TPW + r*14*4096,
          BH(i0),BL(i0), BH(i1),BL(i1), BH(ih),BL(ih), cg);
      linh_t<false><<<dim3(CS/16,4), 256, 0, stream>>>(wbp, BH(ih),BL(ih),
          LO0(3*r+2), LO1(3*r+2), LO2(3*r+2), Lb0+(3*r+2)*64, BH(i0),BL(i0),
          0,0,0, Lb0, (unsigned short*)0, (unsigned short*)0);
      int nh=i0; i0=i1; i1=ih; ih=nh;
    }

    linh_t<true><<<dim3(CS/16,4), 256, 0, stream>>>(wbp, BH(ih),BL(ih),
        LO0(9), LO1(9), LO2(9), Lb0+9*64, BH(i0),BL(i0),
        LO0(10), LO1(10), LO2(10), Lb0+10*64, BH(i1),BL(i1));
    tpf_kernel<<<dim3(CS/16,2), 256, 0, stream>>>(wbp, BH(i0),BL(i0), BH(i1),BL(i1),
        cg, (float*)d_out, nb);
  }
  #undef BH
  #undef BL
  #undef LO0
  #undef LO1
  #undef LO2
}